// Round 1
// baseline (1209.277 us; speedup 1.0000x reference)
//
#include <hip/hip_runtime.h>
#include <hip/hip_bf16.h>

// Problem: B=32, T=256, I=128, H=128, C=100. All fp32.
// out = (h_T + attn_c_final) @ w_fc.T + b_fc, where only the LAST step's
// attention matters (scan carry overwrites attn_c each step).

#define Bsz 32
#define Tsz 256
#define Isz 128
#define Hsz 128
#define Csz 100
#define G4H 512   // 4*H

// ---------------- device helpers ----------------
__device__ __forceinline__ float sigm(float x) {
    return 1.0f / (1.0f + __expf(-x));
}
__device__ __forceinline__ float tanh_s(float x) {
    // stable tanh: e in (0,1], no overflow
    float ax = fabsf(x);
    float e = __expf(-2.0f * ax);
    float t = (1.0f - e) / (1.0f + e);
    return copysignf(t, x);
}

// ---------------- kernel 0: prep (transpose weights, fold biases) ----------------
__global__ __launch_bounds__(256) void prep_kernel(
    const float* __restrict__ w_ih, const float* __restrict__ b_ih,
    const float* __restrict__ w_hh, const float* __restrict__ b_hh,
    float* __restrict__ wih_t, float* __restrict__ whh_t, float* __restrict__ bias) {
    int idx = blockIdx.x * blockDim.x + threadIdx.x;   // 0..65535
    if (idx < G4H * Isz) {
        int j = idx >> 7;      // row in (4H, K) = 0..511
        int k = idx & 127;     // col = 0..127
        wih_t[k * G4H + j] = w_ih[idx];
        whh_t[k * G4H + j] = w_hh[idx];
    }
    if (idx < G4H) bias[idx] = b_ih[idx] + b_hh[idx];
}

// ---------------- generic tiled GEMM: C[M,N] = A[M,K] @ B[K,N] (+bias[N]) ----------------
// 64x64 tile, 256 threads, 4x4 microtile, BK=64. M,N,K multiples of 64/4.
#define BM 64
#define BN 64
#define BKt 64
#define LDP 68   // padded LDS stride (mult of 4 for float4 alignment, breaks 64-stride conflicts)

__global__ __launch_bounds__(256) void gemm_tn(
    const float* __restrict__ A, const float* __restrict__ Bm,
    const float* __restrict__ bias, float* __restrict__ C,
    int M, int N, int K) {
    __shared__ float As[BKt][LDP];   // As[k][m]
    __shared__ float Bs[BKt][LDP];   // Bs[k][n]
    int tid = threadIdx.x;
    int bm = blockIdx.y * BM;
    int bn = blockIdx.x * BN;
    int tx = tid & 15, ty = tid >> 4;
    float acc[4][4] = {};

    int lr = tid >> 4;          // 0..15
    int lc = (tid & 15) * 4;    // 0,4,...,60

    for (int k0 = 0; k0 < K; k0 += BKt) {
        // A tile: rows bm..bm+63, k in [k0,k0+64) -> As[k][m] (transposed store)
        #pragma unroll
        for (int p = 0; p < 4; ++p) {
            int row = p * 16 + lr;
            float4 v = *(const float4*)(A + (size_t)(bm + row) * K + k0 + lc);
            As[lc + 0][row] = v.x;
            As[lc + 1][row] = v.y;
            As[lc + 2][row] = v.z;
            As[lc + 3][row] = v.w;
        }
        // B tile: rows k0..k0+63 of B(K,N), cols bn..bn+63 -> Bs[k][n]
        #pragma unroll
        for (int p = 0; p < 4; ++p) {
            int kr = p * 16 + lr;
            float4 v = *(const float4*)(Bm + (size_t)(k0 + kr) * N + bn + lc);
            *(float4*)&Bs[kr][lc] = v;
        }
        __syncthreads();
        #pragma unroll
        for (int kk = 0; kk < BKt; ++kk) {
            float4 a = *(const float4*)&As[kk][ty * 4];
            float4 b = *(const float4*)&Bs[kk][tx * 4];
            acc[0][0] = fmaf(a.x, b.x, acc[0][0]);
            acc[0][1] = fmaf(a.x, b.y, acc[0][1]);
            acc[0][2] = fmaf(a.x, b.z, acc[0][2]);
            acc[0][3] = fmaf(a.x, b.w, acc[0][3]);
            acc[1][0] = fmaf(a.y, b.x, acc[1][0]);
            acc[1][1] = fmaf(a.y, b.y, acc[1][1]);
            acc[1][2] = fmaf(a.y, b.z, acc[1][2]);
            acc[1][3] = fmaf(a.y, b.w, acc[1][3]);
            acc[2][0] = fmaf(a.z, b.x, acc[2][0]);
            acc[2][1] = fmaf(a.z, b.y, acc[2][1]);
            acc[2][2] = fmaf(a.z, b.z, acc[2][2]);
            acc[2][3] = fmaf(a.z, b.w, acc[2][3]);
            acc[3][0] = fmaf(a.w, b.x, acc[3][0]);
            acc[3][1] = fmaf(a.w, b.y, acc[3][1]);
            acc[3][2] = fmaf(a.w, b.z, acc[3][2]);
            acc[3][3] = fmaf(a.w, b.w, acc[3][3]);
        }
        __syncthreads();
    }
    // epilogue
    float bb[4] = {0.f, 0.f, 0.f, 0.f};
    if (bias) {
        bb[0] = bias[bn + tx * 4 + 0];
        bb[1] = bias[bn + tx * 4 + 1];
        bb[2] = bias[bn + tx * 4 + 2];
        bb[3] = bias[bn + tx * 4 + 3];
    }
    #pragma unroll
    for (int i = 0; i < 4; ++i) {
        int row = bm + ty * 4 + i;
        float4 v;
        v.x = acc[i][0] + bb[0];
        v.y = acc[i][1] + bb[1];
        v.z = acc[i][2] + bb[2];
        v.w = acc[i][3] + bb[3];
        *(float4*)(C + (size_t)row * N + bn + tx * 4) = v;
    }
}

// ---------------- kernel 2: sequential LSTM recurrence, one WG per batch ----------------
// G[b,t,512] precomputed (x@w_ih.T + both biases). whh_t is (K=128, 512).
// Writes H_all[b,t,128] = h_{t+1}.
__global__ __launch_bounds__(256) void lstm_seq(
    const float* __restrict__ G, const float* __restrict__ whh_t,
    float* __restrict__ H_all) {
    int b = blockIdx.x;
    int tid = threadIdx.x;           // 0..255
    __shared__ float h_s[Hsz];
    __shared__ float g_s[G4H];

    if (tid < Hsz) h_s[tid] = 0.0f;
    float c = 0.0f;                  // valid for tid<128
    __syncthreads();

    const float* Gb = G + (size_t)b * Tsz * G4H;
    float* Hb = H_all + (size_t)b * Tsz * Hsz;
    const int col = tid * 2;

    for (int t = 0; t < Tsz; ++t) {
        const float* g_row = Gb + t * G4H;
        float2 g0 = *(const float2*)(g_row + col);
        // 4 independent FMA chains for ILP
        float a0 = g0.x, a1 = g0.y, p0 = 0.f, p1 = 0.f;
        #pragma unroll 16
        for (int k = 0; k < 64; ++k) {
            float hk0 = h_s[k];
            float hk1 = h_s[k + 64];
            float2 w0 = *(const float2*)(whh_t + (size_t)k * G4H + col);
            float2 w1v = *(const float2*)(whh_t + (size_t)(k + 64) * G4H + col);
            a0 = fmaf(hk0, w0.x, a0);
            a1 = fmaf(hk0, w0.y, a1);
            p0 = fmaf(hk1, w1v.x, p0);
            p1 = fmaf(hk1, w1v.y, p1);
        }
        g_s[col] = a0 + p0;
        g_s[col + 1] = a1 + p1;
        __syncthreads();
        if (tid < Hsz) {
            float ig = sigm(g_s[tid]);
            float fg = sigm(g_s[tid + 128]);
            float gg = tanh_s(g_s[tid + 256]);
            float og = sigm(g_s[tid + 384]);
            c = fg * c + ig * gg;
            float h = og * tanh_s(c);
            h_s[tid] = h;
            Hb[t * Hsz + tid] = h;
        }
        __syncthreads();
    }
}

// ---------------- kernel 3: final attention + FC, one WG per batch ----------------
__global__ __launch_bounds__(256) void attn_out(
    const float* __restrict__ H_all, const float* __restrict__ KV,
    const float* __restrict__ w1, const float* __restrict__ w2,
    const float* __restrict__ w_fc, const float* __restrict__ b_fc,
    float* __restrict__ out) {
    int b = blockIdx.x;
    int tid = threadIdx.x;
    __shared__ float hT[Hsz];
    __shared__ float q_s[Hsz];
    __shared__ float s_s[Tsz];
    __shared__ float r_s[Hsz];

    const float* Hb = H_all + (size_t)b * Tsz * Hsz;
    const float* KVb = KV + (size_t)b * Tsz * Hsz;

    if (tid < Hsz) hT[tid] = Hb[255 * Hsz + tid];
    __syncthreads();
    // q = h_T @ w1_top  (w1 rows 0..127, row-major (2H,H))
    if (tid < Hsz) {
        float acc = 0.f;
        #pragma unroll 8
        for (int k = 0; k < Hsz; ++k) acc = fmaf(hT[k], w1[k * Hsz + tid], acc);
        q_s[tid] = acc;
    }
    __syncthreads();
    // scores over memory slots j=0..254 (H_all idx jj holds h_{jj+1})
    int wave = tid >> 6, lane = tid & 63;
    float w2a = w2[lane], w2b = w2[lane + 64];
    for (int j = wave; j < 255; j += 4) {
        const float* kv = KVb + j * Hsz;
        float v0 = q_s[lane] + kv[lane];
        float v1 = q_s[lane + 64] + kv[lane + 64];
        float p = tanh_s(v0) * w2a + tanh_s(v1) * w2b;
        #pragma unroll
        for (int off = 32; off > 0; off >>= 1) p += __shfl_xor(p, off);
        if (lane == 0) s_s[j] = p;
    }
    __syncthreads();
    // attn_c + h_T
    if (tid < Hsz) {
        float acc = 0.f;
        #pragma unroll 4
        for (int j = 0; j < 255; ++j) acc = fmaf(s_s[j], Hb[j * Hsz + tid], acc);
        r_s[tid] = hT[tid] + acc;
    }
    __syncthreads();
    // out = r @ w_fc.T + b_fc
    if (tid < Csz) {
        float acc = b_fc[tid];
        const float* wr = w_fc + tid * Hsz;
        #pragma unroll 8
        for (int k = 0; k < Hsz; ++k) acc = fmaf(r_s[k], wr[k], acc);
        out[b * Csz + tid] = acc;
    }
}

// ---------------- launch ----------------
extern "C" void kernel_launch(void* const* d_in, const int* in_sizes, int n_in,
                              void* d_out, int out_size, void* d_ws, size_t ws_size,
                              hipStream_t stream) {
    const float* x    = (const float*)d_in[0];
    const float* w_ih = (const float*)d_in[1];
    const float* b_ih = (const float*)d_in[2];
    const float* w_hh = (const float*)d_in[3];
    const float* b_hh = (const float*)d_in[4];
    const float* w1   = (const float*)d_in[5];
    const float* w2   = (const float*)d_in[6];
    const float* w_fc = (const float*)d_in[7];
    const float* b_fc = (const float*)d_in[8];

    float* ws = (float*)d_ws;
    float* wih_t = ws;                       // 128*512 = 65536
    float* whh_t = wih_t + 65536;            // 65536
    float* bias  = whh_t + 65536;            // 512
    float* G     = bias + 512;               // 8192*512 = 4194304
    float* H_all = G + 4194304;              // 32*256*128 = 1048576
    float* KV    = H_all + 1048576;          // 1048576
    // total ~25.7 MB of workspace

    prep_kernel<<<256, 256, 0, stream>>>(w_ih, b_ih, w_hh, b_hh, wih_t, whh_t, bias);

    dim3 g1(G4H / BN, (Bsz * Tsz) / BM);     // (8, 128)
    gemm_tn<<<g1, 256, 0, stream>>>(x, wih_t, bias, G, Bsz * Tsz, G4H, Isz);

    lstm_seq<<<Bsz, 256, 0, stream>>>(G, whh_t, H_all);

    dim3 g2(Hsz / BN, (Bsz * Tsz) / BM);     // (2, 128)
    gemm_tn<<<g2, 256, 0, stream>>>(H_all, w1 + Hsz * Hsz, nullptr, KV, Bsz * Tsz, Hsz, Hsz);

    attn_out<<<Bsz, 256, 0, stream>>>(H_all, KV, w1, w2, w_fc, b_fc, (float*)d_out);
}

// Round 2
// 391.619 us; speedup vs baseline: 3.0879x; 3.0879x over previous
//
#include <hip/hip_runtime.h>
#include <hip/hip_bf16.h>

// Problem: B=32, T=256, I=128, H=128, C=100. All fp32.
// out = (h_T + attn_c_final) @ w_fc.T + b_fc; only the LAST step's attention
// matters (scan carry overwrites attn_c each step).

#define Bsz 32
#define Tsz 256
#define Isz 128
#define Hsz 128
#define Csz 100
#define G4H 512   // 4*H

// ---------------- device helpers ----------------
__device__ __forceinline__ float sigm(float x) {
    return 1.0f / (1.0f + __expf(-x));
}
__device__ __forceinline__ float tanh_s(float x) {
    float ax = fabsf(x);
    float e = __expf(-2.0f * ax);
    float t = (1.0f - e) / (1.0f + e);
    return copysignf(t, x);
}

// ---------------- kernel 0: prep (transpose weights, fold biases) ----------------
__global__ __launch_bounds__(256) void prep_kernel(
    const float* __restrict__ w_ih, const float* __restrict__ b_ih,
    const float* __restrict__ w_hh, const float* __restrict__ b_hh,
    float* __restrict__ wih_t, float* __restrict__ whh_t, float* __restrict__ bias) {
    int idx = blockIdx.x * blockDim.x + threadIdx.x;   // 0..65535
    if (idx < G4H * Isz) {
        int j = idx >> 7;      // row in (4H, K) = 0..511
        int k = idx & 127;     // col = 0..127
        wih_t[k * G4H + j] = w_ih[idx];
        whh_t[k * G4H + j] = w_hh[idx];
    }
    if (idx < G4H) bias[idx] = b_ih[idx] + b_hh[idx];
}

// ---------------- generic tiled GEMM: C[M,N] = A[M,K] @ B[K,N] (+bias[N]) ----------------
#define BM 64
#define BN 64
#define BKt 64
#define LDP 68

__global__ __launch_bounds__(256) void gemm_tn(
    const float* __restrict__ A, const float* __restrict__ Bm,
    const float* __restrict__ bias, float* __restrict__ C,
    int M, int N, int K) {
    __shared__ float As[BKt][LDP];   // As[k][m]
    __shared__ float Bs[BKt][LDP];   // Bs[k][n]
    int tid = threadIdx.x;
    int bm = blockIdx.y * BM;
    int bn = blockIdx.x * BN;
    int tx = tid & 15, ty = tid >> 4;
    float acc[4][4] = {};

    int lr = tid >> 4;          // 0..15
    int lc = (tid & 15) * 4;    // 0,4,...,60

    for (int k0 = 0; k0 < K; k0 += BKt) {
        #pragma unroll
        for (int p = 0; p < 4; ++p) {
            int row = p * 16 + lr;
            float4 v = *(const float4*)(A + (size_t)(bm + row) * K + k0 + lc);
            As[lc + 0][row] = v.x;
            As[lc + 1][row] = v.y;
            As[lc + 2][row] = v.z;
            As[lc + 3][row] = v.w;
        }
        #pragma unroll
        for (int p = 0; p < 4; ++p) {
            int kr = p * 16 + lr;
            float4 v = *(const float4*)(Bm + (size_t)(k0 + kr) * N + bn + lc);
            *(float4*)&Bs[kr][lc] = v;
        }
        __syncthreads();
        #pragma unroll
        for (int kk = 0; kk < BKt; ++kk) {
            float4 a = *(const float4*)&As[kk][ty * 4];
            float4 b = *(const float4*)&Bs[kk][tx * 4];
            acc[0][0] = fmaf(a.x, b.x, acc[0][0]);
            acc[0][1] = fmaf(a.x, b.y, acc[0][1]);
            acc[0][2] = fmaf(a.x, b.z, acc[0][2]);
            acc[0][3] = fmaf(a.x, b.w, acc[0][3]);
            acc[1][0] = fmaf(a.y, b.x, acc[1][0]);
            acc[1][1] = fmaf(a.y, b.y, acc[1][1]);
            acc[1][2] = fmaf(a.y, b.z, acc[1][2]);
            acc[1][3] = fmaf(a.y, b.w, acc[1][3]);
            acc[2][0] = fmaf(a.z, b.x, acc[2][0]);
            acc[2][1] = fmaf(a.z, b.y, acc[2][1]);
            acc[2][2] = fmaf(a.z, b.z, acc[2][2]);
            acc[2][3] = fmaf(a.z, b.w, acc[2][3]);
            acc[3][0] = fmaf(a.w, b.x, acc[3][0]);
            acc[3][1] = fmaf(a.w, b.y, acc[3][1]);
            acc[3][2] = fmaf(a.w, b.z, acc[3][2]);
            acc[3][3] = fmaf(a.w, b.w, acc[3][3]);
        }
        __syncthreads();
    }
    float bb[4] = {0.f, 0.f, 0.f, 0.f};
    if (bias) {
        bb[0] = bias[bn + tx * 4 + 0];
        bb[1] = bias[bn + tx * 4 + 1];
        bb[2] = bias[bn + tx * 4 + 2];
        bb[3] = bias[bn + tx * 4 + 3];
    }
    #pragma unroll
    for (int i = 0; i < 4; ++i) {
        int row = bm + ty * 4 + i;
        float4 v;
        v.x = acc[i][0] + bb[0];
        v.y = acc[i][1] + bb[1];
        v.z = acc[i][2] + bb[2];
        v.w = acc[i][3] + bb[3];
        *(float4*)(C + (size_t)row * N + bn + tx * 4) = v;
    }
}

// ---------------- kernel 2: sequential LSTM recurrence, one WG per batch ----------------
// 512 threads: thread (d=tid>>2, q=tid&3) computes all 4 gates of hidden dim d
// over k-slice [32q, 32q+32). Weights held in 128 VGPRs/thread. One barrier
// per step, double-buffered h in LDS, G prefetched one step ahead.
#define HPAD(k) ((k) + 8 * ((k) >> 5))   // bank swizzle: q-slices land on disjoint banks

__global__ __launch_bounds__(512, 2) void lstm_seq(
    const float* __restrict__ G, const float* __restrict__ whh_t,
    float* __restrict__ H_all) {
    const int b = blockIdx.x;
    const int tid = threadIdx.x;      // 0..511
    const int d = tid >> 2;           // 0..127
    const int q = tid & 3;            // 0..3

    __shared__ float h_s[2][160];     // HPAD(127)=151; padded slots never read

    // --- load this thread's weight slice into registers (one-time) ---
    float w[4][32];
    {
        const float* wp = whh_t + (size_t)(q * 32) * G4H + d;
        #pragma unroll
        for (int kk = 0; kk < 32; ++kk) {
            #pragma unroll
            for (int gi = 0; gi < 4; ++gi)
                w[gi][kk] = wp[(size_t)kk * G4H + gi * 128];
        }
    }

    if (tid < 320) ((float*)h_s)[tid] = 0.0f;
    float c = 0.0f;
    __syncthreads();

    const float* Gb = G + (size_t)b * Tsz * G4H + d;
    float* Hb = H_all + (size_t)b * Tsz * Hsz + d;

    // prefetch G row for t=0
    float g0 = Gb[0], g1 = Gb[128], g2 = Gb[256], g3 = Gb[384];

    int cur = 0;
    for (int t = 0; t < Tsz; ++t) {
        // prefetch next step's G row (row 255 re-read at t=255: harmless)
        const int tn = (t < Tsz - 1) ? t + 1 : t;
        const float* grow_n = Gb + (size_t)tn * G4H;
        float n0 = grow_n[0], n1 = grow_n[128], n2 = grow_n[256], n3 = grow_n[384];

        // dot over this thread's k-slice, 4 gate chains
        float a0 = 0.f, a1 = 0.f, a2 = 0.f, a3 = 0.f;
        const float* hb = &h_s[cur][q * 40];   // HPAD(q*32) = q*40, 16B aligned
        #pragma unroll
        for (int kk = 0; kk < 32; kk += 4) {
            float4 h4 = *(const float4*)(hb + kk);
            a0 = fmaf(h4.x, w[0][kk], a0);
            a1 = fmaf(h4.x, w[1][kk], a1);
            a2 = fmaf(h4.x, w[2][kk], a2);
            a3 = fmaf(h4.x, w[3][kk], a3);
            a0 = fmaf(h4.y, w[0][kk + 1], a0);
            a1 = fmaf(h4.y, w[1][kk + 1], a1);
            a2 = fmaf(h4.y, w[2][kk + 1], a2);
            a3 = fmaf(h4.y, w[3][kk + 1], a3);
            a0 = fmaf(h4.z, w[0][kk + 2], a0);
            a1 = fmaf(h4.z, w[1][kk + 2], a1);
            a2 = fmaf(h4.z, w[2][kk + 2], a2);
            a3 = fmaf(h4.z, w[3][kk + 2], a3);
            a0 = fmaf(h4.w, w[0][kk + 3], a0);
            a1 = fmaf(h4.w, w[1][kk + 3], a1);
            a2 = fmaf(h4.w, w[2][kk + 3], a2);
            a3 = fmaf(h4.w, w[3][kk + 3], a3);
        }
        // quad butterfly: every lane of the quad gets the full 128-k dot
        a0 += __shfl_xor(a0, 1);
        a1 += __shfl_xor(a1, 1);
        a2 += __shfl_xor(a2, 1);
        a3 += __shfl_xor(a3, 1);
        a0 += __shfl_xor(a0, 2);
        a1 += __shfl_xor(a1, 2);
        a2 += __shfl_xor(a2, 2);
        a3 += __shfl_xor(a3, 2);

        // redundant elementwise in all 4 lanes (bitwise-identical)
        float iv = sigm(a0 + g0);
        float fv = sigm(a1 + g1);
        float gv = tanh_s(a2 + g2);
        float ov = sigm(a3 + g3);
        c = fv * c + iv * gv;
        float h = ov * tanh_s(c);

        int nxt = cur ^ 1;
        if (q == 0) {
            h_s[nxt][HPAD(d)] = h;
            Hb[(size_t)t * Hsz] = h;
        }
        g0 = n0; g1 = n1; g2 = n2; g3 = n3;
        __syncthreads();
        cur = nxt;
    }
}

// ---------------- kernel 3: final attention + FC, one WG per batch ----------------
__global__ __launch_bounds__(256) void attn_out(
    const float* __restrict__ H_all, const float* __restrict__ KV,
    const float* __restrict__ w1, const float* __restrict__ w2,
    const float* __restrict__ w_fc, const float* __restrict__ b_fc,
    float* __restrict__ out) {
    int b = blockIdx.x;
    int tid = threadIdx.x;
    __shared__ float hT[Hsz];
    __shared__ float q_s[Hsz];
    __shared__ float s_s[Tsz];
    __shared__ float r_s[Hsz];

    const float* Hb = H_all + (size_t)b * Tsz * Hsz;
    const float* KVb = KV + (size_t)b * Tsz * Hsz;

    if (tid < Hsz) hT[tid] = Hb[255 * Hsz + tid];
    __syncthreads();
    if (tid < Hsz) {
        float acc = 0.f;
        #pragma unroll 8
        for (int k = 0; k < Hsz; ++k) acc = fmaf(hT[k], w1[k * Hsz + tid], acc);
        q_s[tid] = acc;
    }
    __syncthreads();
    int wave = tid >> 6, lane = tid & 63;
    float w2a = w2[lane], w2b = w2[lane + 64];
    for (int j = wave; j < 255; j += 4) {
        const float* kv = KVb + j * Hsz;
        float v0 = q_s[lane] + kv[lane];
        float v1 = q_s[lane + 64] + kv[lane + 64];
        float p = tanh_s(v0) * w2a + tanh_s(v1) * w2b;
        #pragma unroll
        for (int off = 32; off > 0; off >>= 1) p += __shfl_xor(p, off);
        if (lane == 0) s_s[j] = p;
    }
    __syncthreads();
    if (tid < Hsz) {
        float acc = 0.f;
        #pragma unroll 4
        for (int j = 0; j < 255; ++j) acc = fmaf(s_s[j], Hb[j * Hsz + tid], acc);
        r_s[tid] = hT[tid] + acc;
    }
    __syncthreads();
    if (tid < Csz) {
        float acc = b_fc[tid];
        const float* wr = w_fc + tid * Hsz;
        #pragma unroll 8
        for (int k = 0; k < Hsz; ++k) acc = fmaf(r_s[k], wr[k], acc);
        out[b * Csz + tid] = acc;
    }
}

// ---------------- launch ----------------
extern "C" void kernel_launch(void* const* d_in, const int* in_sizes, int n_in,
                              void* d_out, int out_size, void* d_ws, size_t ws_size,
                              hipStream_t stream) {
    const float* x    = (const float*)d_in[0];
    const float* w_ih = (const float*)d_in[1];
    const float* b_ih = (const float*)d_in[2];
    const float* w_hh = (const float*)d_in[3];
    const float* b_hh = (const float*)d_in[4];
    const float* w1   = (const float*)d_in[5];
    const float* w2   = (const float*)d_in[6];
    const float* w_fc = (const float*)d_in[7];
    const float* b_fc = (const float*)d_in[8];

    float* ws = (float*)d_ws;
    float* wih_t = ws;                       // 128*512
    float* whh_t = wih_t + 65536;            // 128*512
    float* bias  = whh_t + 65536;            // 512
    float* G     = bias + 512;               // 8192*512
    float* H_all = G + 4194304;              // 32*256*128
    float* KV    = H_all + 1048576;          // 32*256*128

    prep_kernel<<<256, 256, 0, stream>>>(w_ih, b_ih, w_hh, b_hh, wih_t, whh_t, bias);

    dim3 g1(G4H / BN, (Bsz * Tsz) / BM);     // (8, 128)
    gemm_tn<<<g1, 256, 0, stream>>>(x, wih_t, bias, G, Bsz * Tsz, G4H, Isz);

    lstm_seq<<<Bsz, 512, 0, stream>>>(G, whh_t, H_all);

    dim3 g2(Hsz / BN, (Bsz * Tsz) / BM);     // (2, 128)
    gemm_tn<<<g2, 256, 0, stream>>>(H_all, w1 + Hsz * Hsz, nullptr, KV, Bsz * Tsz, Hsz, Hsz);

    attn_out<<<Bsz, 256, 0, stream>>>(H_all, KV, w1, w2, w_fc, b_fc, (float*)d_out);
}

// Round 3
// 355.504 us; speedup vs baseline: 3.4016x; 1.1016x over previous
//
#include <hip/hip_runtime.h>
#include <hip/hip_bf16.h>

// Problem: B=32, T=256, I=128, H=128, C=100. All fp32.
// out = (h_T + attn_c_final) @ w_fc.T + b_fc; only the LAST step's attention
// matters (scan carry overwrites attn_c each step).

#define Bsz 32
#define Tsz 256
#define Isz 128
#define Hsz 128
#define Csz 100
#define G4H 512   // 4*H

// ---------------- device helpers ----------------
__device__ __forceinline__ float2 pk_fma(float2 a, float2 b, float2 c) {
    // d.x = a.x*b.x + c.x ; d.y = a.y*b.y + c.y  (fp32 dual-issue pipe)
    float2 d;
    asm("v_pk_fma_f32 %0, %1, %2, %3" : "=v"(d) : "v"(a), "v"(b), "v"(c));
    return d;
}
// sum across the 4 lanes of a quad via DPP quad_perm (VALU, no LDS pipe)
__device__ __forceinline__ float quad_rsum(float x) {
    int t = __builtin_amdgcn_update_dpp(0, __float_as_int(x), 0xB1, 0xF, 0xF, true); // xor 1
    x += __int_as_float(t);
    t = __builtin_amdgcn_update_dpp(0, __float_as_int(x), 0x4E, 0xF, 0xF, true);     // xor 2
    x += __int_as_float(t);
    return x;
}
__device__ __forceinline__ float rcpf(float x) { return __builtin_amdgcn_rcpf(x); }
__device__ __forceinline__ float sigm_n(float x) { return rcpf(1.0f + __expf(-x)); }
__device__ __forceinline__ float tanh_n(float x) {
    float ax = fabsf(x);
    float e = __expf(-2.0f * ax);
    float t = (1.0f - e) * rcpf(1.0f + e);
    return copysignf(t, x);
}
__device__ __forceinline__ float sigm(float x) { return rcpf(1.0f + __expf(-x)); }
__device__ __forceinline__ float tanh_s(float x) {
    float ax = fabsf(x);
    float e = __expf(-2.0f * ax);
    float t = (1.0f - e) * rcpf(1.0f + e);
    return copysignf(t, x);
}

// ---------------- kernel 0: prep ----------------
// wih_t: (K=128, 512) for gemm1. bias = b_ih + b_hh.
// whh_pk: packed for lstm_seq pk_fma; dest idx bit fields:
//   [1:0]=j4 (k low 2b), [3:2]=q (k-slice), [10:4]=d, [12:11]=gi, [15:13]=kk4
//   source k = q*32 + kk4*4 + j4, source row j = gi*128 + d  (w_hh is (4H,H))
__global__ __launch_bounds__(256) void prep_kernel(
    const float* __restrict__ w_ih, const float* __restrict__ b_ih,
    const float* __restrict__ w_hh, const float* __restrict__ b_hh,
    float* __restrict__ wih_t, float* __restrict__ whh_pk, float* __restrict__ bias) {
    int idx = blockIdx.x * blockDim.x + threadIdx.x;   // 0..65535
    if (idx < G4H * Isz) {
        int j = idx >> 7;      // row in (4H, K)
        int k = idx & 127;
        wih_t[k * G4H + j] = w_ih[idx];

        int j4  = idx & 3;
        int q   = (idx >> 2) & 3;
        int d   = (idx >> 4) & 127;
        int gi  = (idx >> 11) & 3;
        int kk4 = (idx >> 13) & 7;
        whh_pk[idx] = w_hh[(size_t)((gi << 7) + d) * 128 + (q << 5) + (kk4 << 2) + j4];
    }
    if (idx < G4H) bias[idx] = b_ih[idx] + b_hh[idx];
}

// ---------------- generic tiled GEMM: C[M,N] = A[M,K] @ B[K,N] (+bias[N]) ----------------
#define BM 64
#define BN 64
#define BKt 64
#define LDP 68

__global__ __launch_bounds__(256) void gemm_tn(
    const float* __restrict__ A, const float* __restrict__ Bm,
    const float* __restrict__ bias, float* __restrict__ C,
    int M, int N, int K) {
    __shared__ float As[BKt][LDP];   // As[k][m]
    __shared__ float Bs[BKt][LDP];   // Bs[k][n]
    int tid = threadIdx.x;
    int bm = blockIdx.y * BM;
    int bn = blockIdx.x * BN;
    int tx = tid & 15, ty = tid >> 4;
    float acc[4][4] = {};

    int lr = tid >> 4;
    int lc = (tid & 15) * 4;

    for (int k0 = 0; k0 < K; k0 += BKt) {
        #pragma unroll
        for (int p = 0; p < 4; ++p) {
            int row = p * 16 + lr;
            float4 v = *(const float4*)(A + (size_t)(bm + row) * K + k0 + lc);
            As[lc + 0][row] = v.x;
            As[lc + 1][row] = v.y;
            As[lc + 2][row] = v.z;
            As[lc + 3][row] = v.w;
        }
        #pragma unroll
        for (int p = 0; p < 4; ++p) {
            int kr = p * 16 + lr;
            float4 v = *(const float4*)(Bm + (size_t)(k0 + kr) * N + bn + lc);
            *(float4*)&Bs[kr][lc] = v;
        }
        __syncthreads();
        #pragma unroll
        for (int kk = 0; kk < BKt; ++kk) {
            float4 a = *(const float4*)&As[kk][ty * 4];
            float4 b = *(const float4*)&Bs[kk][tx * 4];
            acc[0][0] = fmaf(a.x, b.x, acc[0][0]);
            acc[0][1] = fmaf(a.x, b.y, acc[0][1]);
            acc[0][2] = fmaf(a.x, b.z, acc[0][2]);
            acc[0][3] = fmaf(a.x, b.w, acc[0][3]);
            acc[1][0] = fmaf(a.y, b.x, acc[1][0]);
            acc[1][1] = fmaf(a.y, b.y, acc[1][1]);
            acc[1][2] = fmaf(a.y, b.z, acc[1][2]);
            acc[1][3] = fmaf(a.y, b.w, acc[1][3]);
            acc[2][0] = fmaf(a.z, b.x, acc[2][0]);
            acc[2][1] = fmaf(a.z, b.y, acc[2][1]);
            acc[2][2] = fmaf(a.z, b.z, acc[2][2]);
            acc[2][3] = fmaf(a.z, b.w, acc[2][3]);
            acc[3][0] = fmaf(a.w, b.x, acc[3][0]);
            acc[3][1] = fmaf(a.w, b.y, acc[3][1]);
            acc[3][2] = fmaf(a.w, b.z, acc[3][2]);
            acc[3][3] = fmaf(a.w, b.w, acc[3][3]);
        }
        __syncthreads();
    }
    float bb[4] = {0.f, 0.f, 0.f, 0.f};
    if (bias) {
        bb[0] = bias[bn + tx * 4 + 0];
        bb[1] = bias[bn + tx * 4 + 1];
        bb[2] = bias[bn + tx * 4 + 2];
        bb[3] = bias[bn + tx * 4 + 3];
    }
    #pragma unroll
    for (int i = 0; i < 4; ++i) {
        int row = bm + ty * 4 + i;
        float4 v;
        v.x = acc[i][0] + bb[0];
        v.y = acc[i][1] + bb[1];
        v.z = acc[i][2] + bb[2];
        v.w = acc[i][3] + bb[3];
        *(float4*)(C + (size_t)row * N + bn + tx * 4) = v;
    }
}

// ---------------- kernel 2: sequential LSTM recurrence, one WG per batch ----------------
// 512 threads: thread (d=tid>>2, q=tid&3) computes partial dots of all 4 gates
// of hidden dim d over k-slice [32q, 32q+32) with v_pk_fma_f32, weights in
// 128 VGPRs. Quad DPP reduce; G seed folded into accumulators; one barrier
// per step; double-buffered h in LDS.
#define HPAD(k) ((k) + 8 * ((k) >> 5))   // bank swizzle

__global__ __launch_bounds__(512, 2) void lstm_seq(
    const float* __restrict__ G, const float* __restrict__ whh_pk,
    float* __restrict__ H_all) {
    const int b = blockIdx.x;
    const int tid = threadIdx.x;      // 0..511
    const int d = tid >> 2;           // 0..127
    const int q = tid & 3;            // 0..3

    __shared__ float h_s[2][160];

    // one-time coalesced weight load: w2[gi][kk2] covers k = q*32 + kk2*2 {+0,+1}
    float2 w2[4][16];
    {
        const float4* wp = (const float4*)whh_pk;
        #pragma unroll
        for (int kk4 = 0; kk4 < 8; ++kk4)
            #pragma unroll
            for (int gi = 0; gi < 4; ++gi) {
                float4 v = wp[((kk4 * 4 + gi) * 128 + d) * 4 + q];
                w2[gi][kk4 * 2]     = make_float2(v.x, v.y);
                w2[gi][kk4 * 2 + 1] = make_float2(v.z, v.w);
            }
    }

    if (tid < 320) ((float*)h_s)[tid] = 0.0f;
    float c = 0.0f;
    __syncthreads();

    // lane (d,q) owns G element of gate q, dim d; seeded into acc_q below
    const float* Gq = G + (size_t)b * Tsz * G4H + q * 128 + d;
    float* Hb = H_all + (size_t)b * Tsz * Hsz + d;

    float gval = Gq[0];
    int cur = 0;
    for (int t = 0; t < Tsz; ++t) {
        const int tn = (t < Tsz - 1) ? t + 1 : t;
        float ngval = Gq[(size_t)tn * G4H];   // prefetch, independent of h

        float2 acc0 = make_float2(q == 0 ? gval : 0.f, 0.f);
        float2 acc1 = make_float2(q == 1 ? gval : 0.f, 0.f);
        float2 acc2 = make_float2(q == 2 ? gval : 0.f, 0.f);
        float2 acc3 = make_float2(q == 3 ? gval : 0.f, 0.f);
        const float4* hb4 = (const float4*)&h_s[cur][q * 40];  // HPAD(q*32)=q*40
        #pragma unroll
        for (int kk4 = 0; kk4 < 8; ++kk4) {
            float4 h4 = hb4[kk4];
            float2 hA = make_float2(h4.x, h4.y);
            float2 hB = make_float2(h4.z, h4.w);
            acc0 = pk_fma(hA, w2[0][2 * kk4], acc0);
            acc1 = pk_fma(hA, w2[1][2 * kk4], acc1);
            acc2 = pk_fma(hA, w2[2][2 * kk4], acc2);
            acc3 = pk_fma(hA, w2[3][2 * kk4], acc3);
            acc0 = pk_fma(hB, w2[0][2 * kk4 + 1], acc0);
            acc1 = pk_fma(hB, w2[1][2 * kk4 + 1], acc1);
            acc2 = pk_fma(hB, w2[2][2 * kk4 + 1], acc2);
            acc3 = pk_fma(hB, w2[3][2 * kk4 + 1], acc3);
        }
        float a0 = quad_rsum(acc0.x + acc0.y);   // full 128-k dot + G seed
        float a1 = quad_rsum(acc1.x + acc1.y);
        float a2 = quad_rsum(acc2.x + acc2.y);
        float a3 = quad_rsum(acc3.x + acc3.y);

        float iv = sigm_n(a0);
        float fv = sigm_n(a1);
        float gv = tanh_n(a2);
        float ov = sigm_n(a3);
        c = fv * c + iv * gv;
        float h = ov * tanh_n(c);

        int nxt = cur ^ 1;
        if (q == 0) {
            h_s[nxt][HPAD(d)] = h;
            Hb[(size_t)t * Hsz] = h;
        }
        gval = ngval;
        __syncthreads();
        cur = nxt;
    }
}

// ---------------- kernel 3: final attention + FC, one WG per batch ----------------
__global__ __launch_bounds__(256) void attn_out(
    const float* __restrict__ H_all, const float* __restrict__ KV,
    const float* __restrict__ w1, const float* __restrict__ w2,
    const float* __restrict__ w_fc, const float* __restrict__ b_fc,
    float* __restrict__ out) {
    int b = blockIdx.x;
    int tid = threadIdx.x;
    __shared__ float hT[Hsz];
    __shared__ float q_s[Hsz];
    __shared__ float s_s[Tsz];
    __shared__ float r_s[Hsz];

    const float* Hb = H_all + (size_t)b * Tsz * Hsz;
    const float* KVb = KV + (size_t)b * Tsz * Hsz;

    if (tid < Hsz) hT[tid] = Hb[255 * Hsz + tid];
    __syncthreads();
    if (tid < Hsz) {
        float acc = 0.f;
        #pragma unroll 8
        for (int k = 0; k < Hsz; ++k) acc = fmaf(hT[k], w1[k * Hsz + tid], acc);
        q_s[tid] = acc;
    }
    __syncthreads();
    int wave = tid >> 6, lane = tid & 63;
    float w2a = w2[lane], w2b = w2[lane + 64];
    for (int j = wave; j < 255; j += 4) {
        const float* kv = KVb + j * Hsz;
        float v0 = q_s[lane] + kv[lane];
        float v1 = q_s[lane + 64] + kv[lane + 64];
        float p = tanh_s(v0) * w2a + tanh_s(v1) * w2b;
        #pragma unroll
        for (int off = 32; off > 0; off >>= 1) p += __shfl_xor(p, off);
        if (lane == 0) s_s[j] = p;
    }
    __syncthreads();
    if (tid < Hsz) {
        float acc = 0.f;
        #pragma unroll 4
        for (int j = 0; j < 255; ++j) acc = fmaf(s_s[j], Hb[j * Hsz + tid], acc);
        r_s[tid] = hT[tid] + acc;
    }
    __syncthreads();
    if (tid < Csz) {
        float acc = b_fc[tid];
        const float* wr = w_fc + tid * Hsz;
        #pragma unroll 8
        for (int k = 0; k < Hsz; ++k) acc = fmaf(r_s[k], wr[k], acc);
        out[b * Csz + tid] = acc;
    }
}

// ---------------- launch ----------------
extern "C" void kernel_launch(void* const* d_in, const int* in_sizes, int n_in,
                              void* d_out, int out_size, void* d_ws, size_t ws_size,
                              hipStream_t stream) {
    const float* x    = (const float*)d_in[0];
    const float* w_ih = (const float*)d_in[1];
    const float* b_ih = (const float*)d_in[2];
    const float* w_hh = (const float*)d_in[3];
    const float* b_hh = (const float*)d_in[4];
    const float* w1   = (const float*)d_in[5];
    const float* w2   = (const float*)d_in[6];
    const float* w_fc = (const float*)d_in[7];
    const float* b_fc = (const float*)d_in[8];

    float* ws = (float*)d_ws;
    float* wih_t  = ws;                      // 128*512
    float* whh_pk = wih_t + 65536;           // 128*512 (packed lstm layout)
    float* bias   = whh_pk + 65536;          // 512
    float* G      = bias + 512;              // 8192*512
    float* H_all  = G + 4194304;             // 32*256*128
    float* KV     = H_all + 1048576;         // 32*256*128

    prep_kernel<<<256, 256, 0, stream>>>(w_ih, b_ih, w_hh, b_hh, wih_t, whh_pk, bias);

    dim3 g1(G4H / BN, (Bsz * Tsz) / BM);     // (8, 128)
    gemm_tn<<<g1, 256, 0, stream>>>(x, wih_t, bias, G, Bsz * Tsz, G4H, Isz);

    lstm_seq<<<Bsz, 512, 0, stream>>>(G, whh_pk, H_all);

    dim3 g2(Hsz / BN, (Bsz * Tsz) / BM);     // (2, 128)
    gemm_tn<<<g2, 256, 0, stream>>>(H_all, w1 + Hsz * Hsz, nullptr, KV, Bsz * Tsz, Hsz, Hsz);

    attn_out<<<Bsz, 256, 0, stream>>>(H_all, KV, w1, w2, w_fc, b_fc, (float*)d_out);
}

// Round 4
// 345.523 us; speedup vs baseline: 3.4998x; 1.0289x over previous
//
#include <hip/hip_runtime.h>
#include <hip/hip_bf16.h>

// Problem: B=32, T=256, I=128, H=128, C=100. All fp32.
// out = (h_T + attn_c_final) @ w_fc.T + b_fc; only the LAST step's attention
// matters (scan carry overwrites attn_c each step).

#define Bsz 32
#define Tsz 256
#define Isz 128
#define Hsz 128
#define Csz 100
#define G4H 512   // 4*H

// ---------------- device helpers ----------------
__device__ __forceinline__ float2 pk_fma(float2 a, float2 b, float2 c) {
    float2 d;
    asm("v_pk_fma_f32 %0, %1, %2, %3" : "=v"(d) : "v"(a), "v"(b), "v"(c));
    return d;
}
// sum across the 4 lanes of a quad via DPP quad_perm (VALU pipe, no LDS)
__device__ __forceinline__ float quad_rsum(float x) {
    int t = __builtin_amdgcn_update_dpp(0, __float_as_int(x), 0xB1, 0xF, 0xF, true); // xor 1
    x += __int_as_float(t);
    t = __builtin_amdgcn_update_dpp(0, __float_as_int(x), 0x4E, 0xF, 0xF, true);     // xor 2
    x += __int_as_float(t);
    return x;
}
__device__ __forceinline__ float rcpf(float x) { return __builtin_amdgcn_rcpf(x); }
__device__ __forceinline__ float sigm_n(float x) { return rcpf(1.0f + __expf(-x)); }
__device__ __forceinline__ float tanh_n(float x) {
    float ax = fabsf(x);
    float e = __expf(-2.0f * ax);
    float t = (1.0f - e) * rcpf(1.0f + e);
    return copysignf(t, x);
}
__device__ __forceinline__ float tanh_s(float x) { return tanh_n(x); }

// ---------------- kernel 0: prep ----------------
// wih_t: (K=128, 512) for gemm1. bias = b_ih + b_hh.
// whh_pk: packed for lstm_seq pk_fma; dest idx bit fields:
//   [1:0]=j4, [3:2]=q, [10:4]=d, [12:11]=gi, [15:13]=kk4
//   source k = q*32 + kk4*4 + j4, source row j = gi*128 + d  (w_hh is (4H,H))
__global__ __launch_bounds__(256) void prep_kernel(
    const float* __restrict__ w_ih, const float* __restrict__ b_ih,
    const float* __restrict__ w_hh, const float* __restrict__ b_hh,
    float* __restrict__ wih_t, float* __restrict__ whh_pk, float* __restrict__ bias) {
    int idx = blockIdx.x * blockDim.x + threadIdx.x;   // 0..65535
    if (idx < G4H * Isz) {
        int j = idx >> 7;
        int k = idx & 127;
        wih_t[k * G4H + j] = w_ih[idx];

        int j4  = idx & 3;
        int q   = (idx >> 2) & 3;
        int d   = (idx >> 4) & 127;
        int gi  = (idx >> 11) & 3;
        int kk4 = (idx >> 13) & 7;
        whh_pk[idx] = w_hh[(size_t)((gi << 7) + d) * 128 + (q << 5) + (kk4 << 2) + j4];
    }
    if (idx < G4H) bias[idx] = b_ih[idx] + b_hh[idx];
}

// ---------------- gemm128: C[M,N] = A[M,K] @ B[K,N] (+bias[N]) ----------------
// 128x128 tile, 256 threads, 8x8 microtile, BK=16.
#define GBK 16
#define GLD 132   // padded LDS leading dim

__global__ __launch_bounds__(256) void gemm128(
    const float* __restrict__ A, const float* __restrict__ Bm,
    const float* __restrict__ bias, float* __restrict__ C,
    int M, int N, int K) {
    __shared__ float As[GBK][GLD];   // As[k][m]
    __shared__ float Bs[GBK][GLD];   // Bs[k][n]
    const int tid = threadIdx.x;
    const int bm = blockIdx.y * 128;
    const int bn = blockIdx.x * 128;
    const int tx = tid & 15, ty = tid >> 4;
    float acc[8][8] = {};

    const int ar = tid >> 2;          // 0..63 (A row within half)
    const int ac = (tid & 3) * 4;     // A k-offset
    const int br = tid >> 5;          // 0..7  (B k-row within half)
    const int bc = (tid & 31) * 4;    // B col offset

    for (int k0 = 0; k0 < K; k0 += GBK) {
        #pragma unroll
        for (int h = 0; h < 2; ++h) {
            int r = ar + 64 * h;
            float4 v = *(const float4*)(A + (size_t)(bm + r) * K + k0 + ac);
            As[ac + 0][r] = v.x;
            As[ac + 1][r] = v.y;
            As[ac + 2][r] = v.z;
            As[ac + 3][r] = v.w;
        }
        #pragma unroll
        for (int h = 0; h < 2; ++h) {
            int kr = br + 8 * h;
            float4 v = *(const float4*)(Bm + (size_t)(k0 + kr) * N + bn + bc);
            *(float4*)&Bs[kr][bc] = v;
        }
        __syncthreads();
        #pragma unroll
        for (int kk = 0; kk < GBK; ++kk) {
            float a[8], b[8];
            *(float4*)&a[0] = *(const float4*)&As[kk][ty * 8];
            *(float4*)&a[4] = *(const float4*)&As[kk][ty * 8 + 4];
            *(float4*)&b[0] = *(const float4*)&Bs[kk][tx * 8];
            *(float4*)&b[4] = *(const float4*)&Bs[kk][tx * 8 + 4];
            #pragma unroll
            for (int i = 0; i < 8; ++i)
                #pragma unroll
                for (int j = 0; j < 8; ++j)
                    acc[i][j] = fmaf(a[i], b[j], acc[i][j]);
        }
        __syncthreads();
    }
    float bb[8];
    #pragma unroll
    for (int j = 0; j < 8; ++j) bb[j] = bias ? bias[bn + tx * 8 + j] : 0.0f;
    #pragma unroll
    for (int i = 0; i < 8; ++i) {
        int row = bm + ty * 8 + i;
        float4 v0, v1;
        v0.x = acc[i][0] + bb[0]; v0.y = acc[i][1] + bb[1];
        v0.z = acc[i][2] + bb[2]; v0.w = acc[i][3] + bb[3];
        v1.x = acc[i][4] + bb[4]; v1.y = acc[i][5] + bb[5];
        v1.z = acc[i][6] + bb[6]; v1.w = acc[i][7] + bb[7];
        *(float4*)(C + (size_t)row * N + bn + tx * 8) = v0;
        *(float4*)(C + (size_t)row * N + bn + tx * 8 + 4) = v1;
    }
}

// ---------------- gemm_tn (64-tile, for the small KV gemm) ----------------
#define BM 64
#define BN 64
#define BKt 64
#define LDP 68

__global__ __launch_bounds__(256) void gemm_tn(
    const float* __restrict__ A, const float* __restrict__ Bm,
    const float* __restrict__ bias, float* __restrict__ C,
    int M, int N, int K) {
    __shared__ float As[BKt][LDP];
    __shared__ float Bs[BKt][LDP];
    int tid = threadIdx.x;
    int bm = blockIdx.y * BM;
    int bn = blockIdx.x * BN;
    int tx = tid & 15, ty = tid >> 4;
    float acc[4][4] = {};

    int lr = tid >> 4;
    int lc = (tid & 15) * 4;

    for (int k0 = 0; k0 < K; k0 += BKt) {
        #pragma unroll
        for (int p = 0; p < 4; ++p) {
            int row = p * 16 + lr;
            float4 v = *(const float4*)(A + (size_t)(bm + row) * K + k0 + lc);
            As[lc + 0][row] = v.x;
            As[lc + 1][row] = v.y;
            As[lc + 2][row] = v.z;
            As[lc + 3][row] = v.w;
        }
        #pragma unroll
        for (int p = 0; p < 4; ++p) {
            int kr = p * 16 + lr;
            float4 v = *(const float4*)(Bm + (size_t)(k0 + kr) * N + bn + lc);
            *(float4*)&Bs[kr][lc] = v;
        }
        __syncthreads();
        #pragma unroll
        for (int kk = 0; kk < BKt; ++kk) {
            float4 a = *(const float4*)&As[kk][ty * 4];
            float4 b = *(const float4*)&Bs[kk][tx * 4];
            acc[0][0] = fmaf(a.x, b.x, acc[0][0]);
            acc[0][1] = fmaf(a.x, b.y, acc[0][1]);
            acc[0][2] = fmaf(a.x, b.z, acc[0][2]);
            acc[0][3] = fmaf(a.x, b.w, acc[0][3]);
            acc[1][0] = fmaf(a.y, b.x, acc[1][0]);
            acc[1][1] = fmaf(a.y, b.y, acc[1][1]);
            acc[1][2] = fmaf(a.y, b.z, acc[1][2]);
            acc[1][3] = fmaf(a.y, b.w, acc[1][3]);
            acc[2][0] = fmaf(a.z, b.x, acc[2][0]);
            acc[2][1] = fmaf(a.z, b.y, acc[2][1]);
            acc[2][2] = fmaf(a.z, b.z, acc[2][2]);
            acc[2][3] = fmaf(a.z, b.w, acc[2][3]);
            acc[3][0] = fmaf(a.w, b.x, acc[3][0]);
            acc[3][1] = fmaf(a.w, b.y, acc[3][1]);
            acc[3][2] = fmaf(a.w, b.z, acc[3][2]);
            acc[3][3] = fmaf(a.w, b.w, acc[3][3]);
        }
        __syncthreads();
    }
    float bb[4] = {0.f, 0.f, 0.f, 0.f};
    if (bias) {
        bb[0] = bias[bn + tx * 4 + 0];
        bb[1] = bias[bn + tx * 4 + 1];
        bb[2] = bias[bn + tx * 4 + 2];
        bb[3] = bias[bn + tx * 4 + 3];
    }
    #pragma unroll
    for (int i = 0; i < 4; ++i) {
        int row = bm + ty * 4 + i;
        float4 v;
        v.x = acc[i][0] + bb[0];
        v.y = acc[i][1] + bb[1];
        v.z = acc[i][2] + bb[2];
        v.w = acc[i][3] + bb[3];
        *(float4*)(C + (size_t)row * N + bn + tx * 4) = v;
    }
}

// ---------------- kernel 2: sequential LSTM recurrence, one WG per batch ----------------
// 512 threads: thread (d=tid>>2, q=tid&3) does all 4 gates of dim d over
// k-slice [32q,32q+32) with v_pk_fma_f32, weights in 128 VGPRs.
// KEY: no global stores inside the barrier shadow — h buffered in an 8-step
// LDS ring, flushed as one coalesced float2/thread store every 8 steps
// (the compiler's `s_waitcnt vmcnt(0)` before each s_barrier otherwise
// drains a just-issued store every step).
#define HPAD(k) ((k) + 8 * ((k) >> 5))

__global__ __launch_bounds__(512, 2) void lstm_seq(
    const float* __restrict__ G, const float* __restrict__ whh_pk,
    float* __restrict__ H_all) {
    const int b = blockIdx.x;
    const int tid = threadIdx.x;
    const int d = tid >> 2;
    const int q = tid & 3;

    __shared__ float h_s[2][160];
    __shared__ float ring[8][Hsz];   // last 8 h vectors

    float2 w2v[4][16];
    {
        const float4* wp = (const float4*)whh_pk;
        #pragma unroll
        for (int kk4 = 0; kk4 < 8; ++kk4)
            #pragma unroll
            for (int gi = 0; gi < 4; ++gi) {
                float4 v = wp[((kk4 * 4 + gi) * 128 + d) * 4 + q];
                w2v[gi][kk4 * 2]     = make_float2(v.x, v.y);
                w2v[gi][kk4 * 2 + 1] = make_float2(v.z, v.w);
            }
    }

    if (tid < 320) ((float*)h_s)[tid] = 0.0f;
    float c = 0.0f;
    __syncthreads();

    const float* Gq = G + (size_t)b * Tsz * G4H + q * 128 + d;
    float* Hb = H_all + (size_t)b * Tsz * Hsz;

    // flush-index precompute: thread covers 2 floats of the 8x128 ring
    const int fr = tid >> 6;           // ring row 0..7
    const int fc = (tid * 2) & 127;    // col

    float gval = Gq[0];
    int cur = 0;
    for (int t = 0; t < Tsz; ++t) {
        const int tn = (t < Tsz - 1) ? t + 1 : t;
        float ngval = Gq[(size_t)tn * G4H];   // prefetch, independent of h

        // two 8-deep chains per gate (A: k even-pairs, B: k odd-pairs)
        float2 accA[4], accB[4];
        #pragma unroll
        for (int gi = 0; gi < 4; ++gi) {
            accA[gi] = make_float2(q == gi ? gval : 0.f, 0.f);
            accB[gi] = make_float2(0.f, 0.f);
        }
        const float4* hb4 = (const float4*)&h_s[cur][q * 40];  // HPAD(q*32)=q*40
        #pragma unroll
        for (int kk4 = 0; kk4 < 8; ++kk4) {
            float4 h4 = hb4[kk4];
            float2 hA = make_float2(h4.x, h4.y);
            float2 hB = make_float2(h4.z, h4.w);
            accA[0] = pk_fma(hA, w2v[0][2 * kk4], accA[0]);
            accA[1] = pk_fma(hA, w2v[1][2 * kk4], accA[1]);
            accA[2] = pk_fma(hA, w2v[2][2 * kk4], accA[2]);
            accA[3] = pk_fma(hA, w2v[3][2 * kk4], accA[3]);
            accB[0] = pk_fma(hB, w2v[0][2 * kk4 + 1], accB[0]);
            accB[1] = pk_fma(hB, w2v[1][2 * kk4 + 1], accB[1]);
            accB[2] = pk_fma(hB, w2v[2][2 * kk4 + 1], accB[2]);
            accB[3] = pk_fma(hB, w2v[3][2 * kk4 + 1], accB[3]);
        }
        float a0 = quad_rsum(accA[0].x + accA[0].y + accB[0].x + accB[0].y);
        float a1 = quad_rsum(accA[1].x + accA[1].y + accB[1].x + accB[1].y);
        float a2 = quad_rsum(accA[2].x + accA[2].y + accB[2].x + accB[2].y);
        float a3 = quad_rsum(accA[3].x + accA[3].y + accB[3].x + accB[3].y);

        float iv = sigm_n(a0);
        float fv = sigm_n(a1);
        float gv = tanh_n(a2);
        float ov = sigm_n(a3);
        c = fv * c + iv * gv;
        float h = ov * tanh_n(c);

        int nxt = cur ^ 1;
        if (q == 0) {
            h_s[nxt][HPAD(d)] = h;
            ring[t & 7][d] = h;
        }
        gval = ngval;
        __syncthreads();
        cur = nxt;

        if ((t & 7) == 7) {
            // coalesced chunk flush: rows t-7..t, one float2 per thread.
            // Store stays outstanding across the next ~8 steps; slot not
            // rewritten until t+8, so no race.
            float2 v = *(const float2*)&ring[fr][fc];
            *(float2*)&Hb[(size_t)(t - 7 + fr) * Hsz + fc] = v;
        }
    }
}

// ---------------- kernel 3: final attention + FC, one WG per batch ----------------
__global__ __launch_bounds__(256) void attn_out(
    const float* __restrict__ H_all, const float* __restrict__ KV,
    const float* __restrict__ w1, const float* __restrict__ w2,
    const float* __restrict__ w_fc, const float* __restrict__ b_fc,
    float* __restrict__ out) {
    int b = blockIdx.x;
    int tid = threadIdx.x;
    __shared__ float hT[Hsz];
    __shared__ float q_s[Hsz];
    __shared__ float w2s[Hsz];
    __shared__ float s_s[Tsz];
    __shared__ float r2[2][Hsz];
    __shared__ float r_s[Hsz];

    const float* Hb = H_all + (size_t)b * Tsz * Hsz;
    const float* KVb = KV + (size_t)b * Tsz * Hsz;

    if (tid < Hsz) {
        hT[tid] = Hb[255 * Hsz + tid];
        w2s[tid] = w2[tid];
    }
    __syncthreads();
    if (tid < Hsz) {
        float acc = 0.f;
        #pragma unroll 8
        for (int k = 0; k < Hsz; ++k) acc = fmaf(hT[k], w1[k * Hsz + tid], acc);
        q_s[tid] = acc;
    }
    __syncthreads();

    // scores: quad-per-j, DPP-only reduction (no ds_swizzle chain)
    const int qd = tid >> 2, ql = tid & 3;
    #pragma unroll
    for (int jj = 0; jj < 4; ++jj) {
        int j = qd + jj * 64;
        float p = 0.f;
        if (j < 255) {
            const float* kv = KVb + (size_t)j * Hsz + ql * 32;
            const float* qs = q_s + ql * 32;
            const float* wv = w2s + ql * 32;
            #pragma unroll 8
            for (int k = 0; k < 32; ++k)
                p = fmaf(tanh_s(qs[k] + kv[k]), wv[k], p);
        }
        p = quad_rsum(p);   // uniform per quad: no divergence inside
        if (ql == 0 && j < 255) s_s[j] = p;
    }
    __syncthreads();

    // attn_c split across two halves of the j range
    {
        int dd = tid & 127, half = tid >> 7;
        int j0 = half * 128, je = half ? 255 : 128;
        float acc = 0.f;
        #pragma unroll 4
        for (int j = j0; j < je; ++j) acc = fmaf(s_s[j], Hb[(size_t)j * Hsz + dd], acc);
        r2[half][dd] = acc;
    }
    __syncthreads();
    if (tid < Hsz) r_s[tid] = hT[tid] + r2[0][tid] + r2[1][tid];
    __syncthreads();

    // out = r @ w_fc.T + b_fc : 2 threads per output, shfl combine
    {
        int o = tid >> 1, half = tid & 1;
        float acc = 0.f;
        if (o < Csz) {
            const float* wr = w_fc + (size_t)o * Hsz + half * 64;
            const float* rr = r_s + half * 64;
            #pragma unroll 8
            for (int k = 0; k < 64; ++k) acc = fmaf(rr[k], wr[k], acc);
        }
        acc += __shfl_xor(acc, 1);
        if (half == 0 && o < Csz) out[b * Csz + o] = acc + b_fc[o];
    }
}

// ---------------- launch ----------------
extern "C" void kernel_launch(void* const* d_in, const int* in_sizes, int n_in,
                              void* d_out, int out_size, void* d_ws, size_t ws_size,
                              hipStream_t stream) {
    const float* x    = (const float*)d_in[0];
    const float* w_ih = (const float*)d_in[1];
    const float* b_ih = (const float*)d_in[2];
    const float* w_hh = (const float*)d_in[3];
    const float* b_hh = (const float*)d_in[4];
    const float* w1   = (const float*)d_in[5];
    const float* w2   = (const float*)d_in[6];
    const float* w_fc = (const float*)d_in[7];
    const float* b_fc = (const float*)d_in[8];

    float* ws = (float*)d_ws;
    float* wih_t  = ws;                      // 128*512
    float* whh_pk = wih_t + 65536;           // 128*512 (packed lstm layout)
    float* bias   = whh_pk + 65536;          // 512
    float* G      = bias + 512;              // 8192*512
    float* H_all  = G + 4194304;             // 32*256*128
    float* KV     = H_all + 1048576;         // 32*256*128

    prep_kernel<<<256, 256, 0, stream>>>(w_ih, b_ih, w_hh, b_hh, wih_t, whh_pk, bias);

    dim3 g1(G4H / 128, (Bsz * Tsz) / 128);   // (4, 64)
    gemm128<<<g1, 256, 0, stream>>>(x, wih_t, bias, G, Bsz * Tsz, G4H, Isz);

    lstm_seq<<<Bsz, 512, 0, stream>>>(G, whh_pk, H_all);

    dim3 g2(Hsz / BN, (Bsz * Tsz) / BM);     // (2, 128)
    gemm_tn<<<g2, 256, 0, stream>>>(H_all, w1 + Hsz * Hsz, nullptr, KV, Bsz * Tsz, Hsz, Hsz);

    attn_out<<<Bsz, 256, 0, stream>>>(H_all, KV, w1, w2, w_fc, b_fc, (float*)d_out);
}